// Round 10
// baseline (80.731 us; speedup 1.0000x reference)
//
#include <hip/hip_runtime.h>

#define TPB 256

typedef __attribute__((ext_vector_type(8))) short short8;
typedef __attribute__((ext_vector_type(4))) float f32x4;

__device__ __forceinline__ unsigned f2bf_pk(float a, float b) {
  return ((__float_as_uint(a) + 0x8000u) >> 16) | ((__float_as_uint(b) + 0x8000u) & 0xffff0000u);
}
__device__ __forceinline__ float bflo(unsigned v) { return __uint_as_float(v << 16); }
__device__ __forceinline__ float bfhi(unsigned v) { return __uint_as_float(v & 0xffff0000u); }

// async global->LDS DMA, 16 B per lane (wave-uniform LDS base + lane*16)
__device__ __forceinline__ void dma16(const void* g, void* l) {
  __builtin_amdgcn_global_load_lds(
      (const __attribute__((address_space(1))) unsigned*)g,
      (__attribute__((address_space(3))) unsigned*)l, 16, 0, 0);
}

// xor-16 butterfly add via ds_swizzle (BitMode: xor=16, and=31) — one DS op,
// no bpermute address setup.
__device__ __forceinline__ float swz16_add(float v) {
  int t = __builtin_amdgcn_ds_swizzle(__float_as_int(v), 0x401F);
  return v + __int_as_float(t);
}

// ---- prep: permuted bf16 A-fragment table (row permute makes each lane's
// 18x4 accumulator exactly 8 cin x 9 k for one pixel) ----------------------
__global__ void prep_kernel(const float* __restrict__ Wp, unsigned* __restrict__ Wq) {
  int idx = blockIdx.x * blockDim.x + threadIdx.x;  // 147456 u32
  if (idx >= 32 * 18 * 64 * 4) return;
  int j2   = idx & 3;
  int lane = (idx >> 2) & 63;
  int rt   = (idx >> 8) % 18;
  int o    = (idx >> 8) / 18;
  int m16 = lane & 15, kq = lane >> 4;
  int row = o * 288 + (m16 >> 2) * 72 + rt * 4 + (m16 & 3);
  const float* src = Wp + row * 32 + kq * 8 + j2 * 2;
  Wq[idx] = f2bf_pk(src[0], src[1]);
}

// ---- main: 1024 blocks = exactly 4/CU (16 waves/CU). LDS pipe carries only
// A-frags + x-tile taps + butterflies; all broadcast-friendly small tensors
// (predictor bias C-operand, dyn-bias weights, couts bias) come straight
// from global on the otherwise-idle VMEM pipe (L1/L2-resident).
template <bool USE_WQ>
__global__ __launch_bounds__(TPB, 4) void dppc10_kernel(
    const float* __restrict__ x, const float* __restrict__ Wp,
    const float* __restrict__ bp, const unsigned* __restrict__ Wq,
    float* __restrict__ out) {
  // [r 0..2][ww 0..65][c 0..31 pad40], bf16; stride 40 shorts = 80 B
  __shared__ __align__(16) unsigned short xrow2[3 * 66 * 40];   // 15840 B
  __shared__ __align__(16) char wqbuf[18432];                   // 18432 B

  const int tid = threadIdx.x;
  const int bid = blockIdx.x;
  const int og  = bid & 7;      // couts og*4 .. og*4+3
  const int t   = bid >> 3;
  const int b   = t >> 6;
  const int h   = t & 63;

  const char* wq_g = (const char*)Wq + (size_t)(og * 4) * 18432;

  // kick off DMA for o=0 immediately; it completes under the prelude
  if (USE_WQ) {
    for (int c = tid; c < 1152; c += TPB)
      dma16(wq_g + c * 16, wqbuf + c * 16);
  }

  // prelude: side-halo zero words (disjoint from interior) + interior stage
  for (int i = tid; i < 120; i += TPB) {      // 6 (r,ww-halo) slots x 20 words
    int p = i / 20, w = i % 20;
    ((unsigned*)xrow2)[(((p >> 1) * 66 + ((p & 1) ? 65 : 0)) * 20) + w] = 0;
  }
  for (int i = tid; i < 1536; i += TPB) {     // r(3) x c4(8) x px(64)
    int px_ = i & 63, c4 = (i >> 6) & 7, r = i >> 9;
    int hh = h - 1 + r;
    unsigned w0 = 0, w1 = 0;
    if ((unsigned)hh < 64u) {
      const float* xp = x + ((b * 32 + c4 * 4) * 64 + hh) * 64 + px_;
      float f0 = xp[0], f1 = xp[4096], f2 = xp[8192], f3 = xp[12288];
      w0 = f2bf_pk(f0, f1);
      w1 = f2bf_pk(f2, f3);
    }
    uint2* dst = (uint2*)&xrow2[(r * 66 + 1 + px_) * 40 + c4 * 4];
    *dst = make_uint2(w0, w1);
  }
  __syncthreads();   // drains prelude stores AND the o=0 DMA

  const int lane = tid & 63;
  const int wv   = tid >> 6;
  const int m16  = lane & 15, kq = lane >> 4;
  const int px   = wv * 16 + m16;

#pragma unroll 1
  for (int oo = 0; oo < 4; ++oo) {
    const int o = og * 4 + oo;
    const float* bp_o = bp + og * 1152 + oo * 288;   // C-operand slice (global)

    // B fragment re-read each o (keeps it out of the long-lived reg set)
    const short8 bfrag = *(const short8*)&xrow2[(66 + 1 + px) * 40 + kq * 8];

    // phase 1: 18 MFMAs, predictor bias folded into C-operand (global b128,
    // 16-lane broadcast, L1/L2-hit; VMEM pipe).
    // lane holds pred fp32 for idx=c8*9+k (cin=kq*8+c8) at px: acc[idx>>2][idx&3]
    f32x4 acc[18];
    if (USE_WQ) {
#pragma unroll
      for (int rt = 0; rt < 18; ++rt) {
        const short8 a = *(const short8*)(wqbuf + (rt * 64 + lane) * 16);
        const f32x4 bb = *(const f32x4*)(bp_o + kq * 72 + rt * 4);
        acc[rt] = __builtin_amdgcn_mfma_f32_16x16x32_bf16(a, bfrag, bb, 0, 0, 0);
      }
    } else {
      const float* ab = Wp + (o * 288 + (m16 >> 2) * 72 + (m16 & 3)) * 32 + kq * 8;
#pragma unroll
      for (int rt = 0; rt < 18; ++rt) {
        const float* ap = ab + rt * 4 * 32;
        float4 a0 = *(const float4*)ap;
        float4 a1 = *(const float4*)(ap + 4);
        union { short8 v; unsigned u[4]; } af;
        af.u[0] = f2bf_pk(a0.x, a0.y);
        af.u[1] = f2bf_pk(a0.z, a0.w);
        af.u[2] = f2bf_pk(a1.x, a1.y);
        af.u[3] = f2bf_pk(a1.z, a1.w);
        const f32x4 bb = *(const f32x4*)(bp_o + kq * 72 + rt * 4);
        acc[rt] = __builtin_amdgcn_mfma_f32_16x16x32_bf16(af.v, bfrag, bb, 0, 0, 0);
      }
    }

    // single-buffer handoff: all waves done reading wqbuf, then start DMA
    // for o+1; it rides under the entire norm phase below.
    if (USE_WQ && oo < 3) {
      __syncthreads();
      const char* g = wq_g + (size_t)(oo + 1) * 18432;
      for (int c = tid; c < 1152; c += TPB)
        dma16(g + c * 16, wqbuf + c * 16);
    }

    // cin-norm denominators: local partial + butterfly across kq (bits 4,5)
    float rinv[9];
#pragma unroll
    for (int kk = 0; kk < 9; ++kk) rinv[kk] = 0.f;
#pragma unroll
    for (int c8 = 0; c8 < 8; ++c8)
#pragma unroll
      for (int kk = 0; kk < 9; ++kk) {
        const int idx = c8 * 9 + kk;
        const float v = acc[idx >> 2][idx & 3];
        rinv[kk] += v * v;
      }
#pragma unroll
    for (int kk = 0; kk < 9; ++kk) {
      float s = swz16_add(rinv[kk]);
      s += __shfl_xor(s, 32);
      rinv[kk] = rsqrtf(fmaxf(s, 1e-24f));  // == 1/max(sqrt(s),1e-12)
    }

    // pass B: per tap k one b128 patch read (px-major x-tile), s2/dot
    // accumulated per c8; k-norm applied in the epilogue.
    float s2[8], dot[8];
#pragma unroll
    for (int c8 = 0; c8 < 8; ++c8) { s2[c8] = 0.f; dot[c8] = 0.f; }
#pragma unroll
    for (int kk = 0; kk < 9; ++kk) {
      const int kh = kk / 3, kw = kk - kh * 3;
      const uint4 tp = *(const uint4*)&xrow2[(kh * 66 + kw + px) * 40 + kq * 8];
      const float rv = rinv[kk];
#pragma unroll
      for (int c8 = 0; c8 < 8; ++c8) {
        const int idx = c8 * 9 + kk;
        const float tv = acc[idx >> 2][idx & 3] * rv;
        s2[c8] += tv * tv;
        const unsigned wd = ((const unsigned*)&tp)[c8 >> 1];
        const float pv = (c8 & 1) ? bfhi(wd) : bflo(wd);
        dot[c8] += tv * pv;
      }
    }

    // epilogue: combine per-c8, dyn-bias weights from global (VMEM, L1-hit),
    // butterfly, store with uniform couts-bias from global.
    const float4 wb0 = *(const float4*)(Wp + (9216 + o) * 32 + kq * 8);
    const float4 wb1 = *(const float4*)(Wp + (9216 + o) * 32 + kq * 8 + 4);
    const uint4 tc = *(const uint4*)&xrow2[(66 + 1 + px) * 40 + kq * 8];  // center tap
    float oacc = 0.f;
#pragma unroll
    for (int c8 = 0; c8 < 8; ++c8) {
      oacc += rsqrtf(fmaxf(s2[c8], 1e-24f)) * dot[c8];
      const unsigned wd = ((const unsigned*)&tc)[c8 >> 1];
      const float xc = (c8 & 1) ? bfhi(wd) : bflo(wd);
      const float wbv = (c8 < 4) ? ((const float*)&wb0)[c8] : ((const float*)&wb1)[c8 - 4];
      oacc += wbv * xc;
    }
    oacc = swz16_add(oacc);
    oacc += __shfl_xor(oacc, 32);
    if (kq == 0)
      out[((b * 32 + o) * 64 + h) * 64 + px] = oacc + bp[9216 + o];

    // drain DMA(o+1) + make wqbuf writes visible before next MFMA phase
    if (oo < 3) __syncthreads();
  }
}

extern "C" void kernel_launch(void* const* d_in, const int* in_sizes, int n_in,
                              void* d_out, int out_size, void* d_ws, size_t ws_size,
                              hipStream_t stream) {
  const float* x  = (const float*)d_in[0];
  const float* Wp = (const float*)d_in[1];
  const float* bp = (const float*)d_in[2];
  float* out = (float*)d_out;
  const size_t wq_bytes = (size_t)32 * 18 * 64 * 8 * 2;  // 589824
  if (ws_size >= wq_bytes) {
    prep_kernel<<<576, 256, 0, stream>>>(Wp, (unsigned*)d_ws);
    dppc10_kernel<true><<<1024, TPB, 0, stream>>>(x, Wp, bp, (const unsigned*)d_ws, out);
  } else {
    dppc10_kernel<false><<<1024, TPB, 0, stream>>>(x, Wp, bp, nullptr, out);
  }
}